// Round 5
// baseline (371.732 us; speedup 1.0000x reference)
//
#include <hip/hip_runtime.h>

// CTC loss forward, B=64 T=1000 V=64 L=150 (S=2L+1=301)
// d_in[0]: logits f32 [B,T,V]; d_in[1]: audio_length i32 [B]; d_in[2]: labels i32 [B,L]
// d_out: scalar f32 (mean loss). d_ws: sumlse[B] f64.
//
// fwd/bwd split (2 waves/example). Exp-domain fp64 alpha/beta in registers.
// Emissions staged through LDS via global_load_lds (per-lane gather source,
// state-indexed layout), 8-frame prefetch depth, counted vmcnt waits.
// Constant emission shift C2F keeps magnitudes in fp64 range; renorm/64 steps.

#define VV 64
#define L2E 1.4426950408889634f
#define C2F 6.72f                 // constant emission shift (log2 units)
#define LN2D 0.6931471805599453
#define PF 8                      // prefetch depth (frames)
#define RS 16                     // LDS ring slots

typedef float __attribute__((address_space(1))) gfloat;
typedef float __attribute__((address_space(3))) sfloat;

__device__ __forceinline__ void stage_row(const float* g, float* l) {
    __builtin_amdgcn_global_load_lds((const gfloat*)g, (sfloat*)l, 4, 0, 0);
}

// ---------------- Kernel A: per-frame lse, block-reduced, 1 atomic/block ---
__global__ __launch_bounds__(256) void lse_kernel(const float4* __restrict__ lg4,
                                                  const int* __restrict__ audio_len,
                                                  double* __restrict__ sumlse,
                                                  float* __restrict__ out,
                                                  int T) {
    if (blockIdx.x == 0 && blockIdx.y == 0 && threadIdx.x == 0) out[0] = 0.0f;
    const int b = blockIdx.y;
    const int tl = threadIdx.x >> 4;   // local frame 0..15
    const int q = threadIdx.x & 15;
    const int t = blockIdx.x * 16 + tl;
    int al = audio_len[b];
    int Tb = ((al + 128) >> 7) >> 1;
    if (Tb < 1) Tb = 1;
    if (Tb > T) Tb = T;

    __shared__ double part[16];
    double v = 0.0;
    if (t < Tb) {
        float4 x = lg4[((size_t)b * T + t) * 16 + q];
        float m = fmaxf(fmaxf(x.x, x.y), fmaxf(x.z, x.w));
        #pragma unroll
        for (int off = 8; off >= 1; off >>= 1) m = fmaxf(m, __shfl_xor(m, off));
        float s = __expf(x.x - m) + __expf(x.y - m) + __expf(x.z - m) + __expf(x.w - m);
        #pragma unroll
        for (int off = 8; off >= 1; off >>= 1) s += __shfl_xor(s, off);
        v = (double)(m + __logf(s));
    }
    if (q == 0) part[tl] = v;
    __syncthreads();
    if (threadIdx.x == 0) {
        double s = 0.0;
        #pragma unroll
        for (int i = 0; i < 16; ++i) s += part[i];
        if (s != 0.0) atomicAdd(&sumlse[b], s);
    }
}

// ---------------- Kernel B: fwd+bwd recursion, 2 waves per example ---------

#define RENORM()                                                                \
    do {                                                                        \
        double mx_ = fmax(fmax(fmax(p[0], p[1]), fmax(p[2], p[3])), p[4]);      \
        int ex_ = (__double2hiint(mx_) >> 20) & 0x7ff;                          \
        _Pragma("unroll")                                                       \
        for (int o_ = 32; o_ >= 1; o_ >>= 1) {                                  \
            int t_ = __shfl_xor(ex_, o_);                                       \
            ex_ = t_ > ex_ ? t_ : ex_;                                          \
        }                                                                       \
        if (ex_ > 0) {                                                          \
            Cexp += ex_ - 1023;                                                 \
            double r_ = __hiloint2double((2046 - ex_) << 20, 0);                \
            _Pragma("unroll")                                                   \
            for (int i_ = 0; i_ < 5; ++i_) p[i_] *= r_;                         \
        }                                                                       \
    } while (0)

__global__ __launch_bounds__(128) void ctc_kernel(const float* __restrict__ lgall,
                                                  const int* __restrict__ audio_len,
                                                  const int* __restrict__ labels,
                                                  const double* __restrict__ sumlse,
                                                  float* __restrict__ out,
                                                  int B, int T, int L) {
    const int b = blockIdx.x;
    const int tid = threadIdx.x;
    const int lane = tid & 63;
    const int wid = tid >> 6;
    const int S = 2 * L + 1;
    const float* lg = lgall + (size_t)b * T * VV;

    int al = audio_len[b];
    int Tb = ((al + 128) >> 7) >> 1;
    if (Tb < 1) Tb = 1;
    if (Tb > T) Tb = T;
    const int tf = Tb - 1;
    const int mid = tf >> 1;   // fwd steps: frames 1..mid ; bwd: frames tf..mid+1

    __shared__ float ebuf[2][RS][5 * VV];   // state-indexed: word i*64+l = state 5l+i
    __shared__ int lab_sh[152];
    __shared__ double beta_sh[324];
    __shared__ double sumlse_sh;
    __shared__ int cexpb_sh;

    for (int k = tid; k < L; k += 128) lab_sh[k] = labels[b * L + k];
    __syncthreads();

    int cnt = 0;
    for (int k = lane; k < L; k += 64) cnt += (lab_sh[k] >= 0) ? 1 : 0;
    #pragma unroll
    for (int off = 32; off >= 1; off >>= 1) cnt += __shfl_xor(cnt, off);
    const int s_last = 2 * cnt;

    // per-state symbols (states 5*lane+i) and skip flags (i up to 6 for bwd)
    int sym[5];
    double skd[7];
    #pragma unroll
    for (int i = 0; i < 7; ++i) {
        int s = lane * 5 + i;
        int sy = 0;
        double sk = 0.0;
        if (s < S && (s & 1)) {
            int lv = lab_sh[s >> 1];
            sy = lv < 0 ? 0 : lv;
            if (s >= 3 && sy != 0) {
                int lv2 = lab_sh[(s >> 1) - 1];
                int s2 = lv2 < 0 ? 0 : lv2;
                sk = (sy != s2) ? 1.0 : 0.0;
            }
        }
        if (i < 5) sym[i] = sy;
        skd[i] = sk;
    }

    double p[5];
    int Cexp = 0;
    float* myb = &ebuf[wid][0][0];

    int start, dir, nst;
    if (wid == 0) { start = 1; dir = 1; nst = mid; }
    else          { start = tf; dir = -1; nst = tf - mid; }

    // init
    if (wid == 0) {
        #pragma unroll
        for (int i = 0; i < 5; ++i) {
            float x = lg[sym[i]];   // t=0 row gather
            int s = lane * 5 + i;
            p[i] = (s <= 1) ? (double)__builtin_amdgcn_exp2f(fmaf(x, L2E, -C2F)) : 0.0;
        }
    } else {
        #pragma unroll
        for (int i = 0; i < 5; ++i) {
            int s = lane * 5 + i;
            p[i] = (s == s_last || s == s_last - 1) ? 1.0 : 0.0;
        }
    }

    // prologue: stage sequence positions 0..PF-1
    #pragma unroll
    for (int j = 0; j < PF; ++j) {
        int ft = start + dir * j;
        if (ft < 0) ft = 0;
        if (ft > tf) ft = tf;
        const float* base = lg + ((size_t)ft << 6);
        float* dst = myb + (j & (RS - 1)) * (5 * VV);
        #pragma unroll
        for (int i = 0; i < 5; ++i) stage_row(base + sym[i], dst + i * VV);
    }
    asm volatile("s_waitcnt vmcnt(35)" ::: "memory");

    float feC[7], feN[7];
    {   // pre-read position 0
        float* src = myb;
        #pragma unroll
        for (int i = 0; i < 5; ++i) feC[i] = src[i * VV + lane];
        feC[5] = src[lane + 1];
        feC[6] = src[VV + lane + 1];
    }

    for (int k = 0; k < nst; ++k) {
        // cross-lane deps of this step (previous p) — issue first
        double a_, b_;
        if (wid == 0) {
            a_ = __shfl_up(p[4], 1);
            b_ = __shfl_up(p[3], 1);
            if (lane == 0) { a_ = 0.0; b_ = 0.0; }
        } else {
            a_ = __shfl_down(p[0], 1);
            b_ = __shfl_down(p[1], 1);
            if (lane == 63) { a_ = 0.0; b_ = 0.0; }
        }
        // stage position k+PF
        {
            int ft = start + dir * (k + PF);
            if (ft < 0) ft = 0;
            if (ft > tf) ft = tf;
            const float* base = lg + ((size_t)ft << 6);
            float* dst = myb + ((k + PF) & (RS - 1)) * (5 * VV);
            #pragma unroll
            for (int i = 0; i < 5; ++i) stage_row(base + sym[i], dst + i * VV);
        }
        asm volatile("s_waitcnt vmcnt(35)" ::: "memory");   // position k+1 staged
        // read next position's emissions (for step k+1)
        {
            float* src = myb + ((k + 1) & (RS - 1)) * (5 * VV);
            #pragma unroll
            for (int i = 0; i < 5; ++i) feN[i] = src[i * VV + lane];
            feN[5] = src[lane + 1];
            feN[6] = src[VV + lane + 1];
        }
        // compute with feC (position k)
        double e_[5];
        #pragma unroll
        for (int i = 0; i < 5; ++i)
            e_[i] = (double)__builtin_amdgcn_exp2f(fmaf(feC[i], L2E, -C2F));
        if (wid == 0) {
            double n0 = e_[0] * (p[0] + a_ + skd[0] * b_);
            double n1 = e_[1] * (p[1] + p[0] + skd[1] * a_);
            double n2 = e_[2] * (p[2] + p[1] + skd[2] * p[0]);
            double n3 = e_[3] * (p[3] + p[2] + skd[3] * p[1]);
            double n4 = e_[4] * (p[4] + p[3] + skd[4] * p[2]);
            p[0] = n0; p[1] = n1; p[2] = n2; p[3] = n3; p[4] = n4;
        } else {
            double u0 = p[0] * e_[0];
            double u1 = p[1] * e_[1];
            double u2 = p[2] * e_[2];
            double u3 = p[3] * e_[3];
            double u4 = p[4] * e_[4];
            double u5 = a_ * (double)__builtin_amdgcn_exp2f(fmaf(feC[5], L2E, -C2F));
            double u6 = b_ * (double)__builtin_amdgcn_exp2f(fmaf(feC[6], L2E, -C2F));
            double n0 = u0 + u1 + skd[2] * u2;
            double n1 = u1 + u2 + skd[3] * u3;
            double n2 = u2 + u3 + skd[4] * u4;
            double n3 = u3 + u4 + skd[5] * u5;
            double n4 = u4 + u5 + skd[6] * u6;
            p[0] = n0; p[1] = n1; p[2] = n2; p[3] = n3; p[4] = n4;
        }
        #pragma unroll
        for (int i = 0; i < 7; ++i) feC[i] = feN[i];
        if (((k + 1) & 63) == 0) RENORM();
    }
    RENORM();   // normalize before the dot product

    if (wid == 1) {
        #pragma unroll
        for (int i = 0; i < 5; ++i) beta_sh[lane * 5 + i] = p[i];
        if (lane == 0) { cexpb_sh = Cexp; sumlse_sh = sumlse[b]; }
    }
    __syncthreads();

    if (wid == 0) {
        double dot = 0.0;
        #pragma unroll
        for (int i = 0; i < 5; ++i) dot += p[i] * beta_sh[lane * 5 + i];
        #pragma unroll
        for (int o = 32; o >= 1; o >>= 1) dot += __shfl_xor(dot, o);
        if (lane == 0) {
            dot = fmax(dot, 1e-290);
            // Tb emission-shift factors of 2^-C2F were applied in total
            double lp = log(dot) + (double)(Cexp + cexpb_sh) * LN2D
                        + (double)Tb * (double)C2F * LN2D - sumlse_sh;
            atomicAdd(out, (float)(-lp / (double)B));
        }
    }
}

extern "C" void kernel_launch(void* const* d_in, const int* in_sizes, int n_in,
                              void* d_out, int out_size, void* d_ws, size_t ws_size,
                              hipStream_t stream) {
    const float* logits = (const float*)d_in[0];
    const int* audio = (const int*)d_in[1];
    const int* labels = (const int*)d_in[2];
    float* out = (float*)d_out;

    int B = in_sizes[1];
    int L = in_sizes[2] / B;
    int T = in_sizes[0] / (B * VV);

    double* sumlse = (double*)d_ws;   // B doubles
    hipMemsetAsync(sumlse, 0, (size_t)B * sizeof(double), stream);

    dim3 gA((T + 15) / 16, B);
    lse_kernel<<<gA, 256, 0, stream>>>((const float4*)logits, audio, sumlse, out, T);
    ctc_kernel<<<B, 128, 0, stream>>>(logits, audio, labels, sumlse, out, B, T, L);
}

// Round 6
// 169.812 us; speedup vs baseline: 2.1891x; 2.1891x over previous
//
#include <hip/hip_runtime.h>

// CTC loss forward, B=64 T=1000 V=64 L=150 (S=2L+1=301)
// d_in[0]: logits f32 [B,T,V]; d_in[1]: audio_length i32 [B]; d_in[2]: labels i32 [B,L]
// d_out: scalar f32 (mean loss). d_ws: sumlse[B] f64.
//
// fwd/bwd split: wave 0 runs alpha from t=0 to mid, wave 1 runs beta from
// t=Tf down to mid+1; loss from sum_s alpha_mid(s)*beta_mid(s).
// Exp-domain fp64 state, emissions e^logit converted to f32 probabilities in
// the prefetch phase (CONV), power-of-2 wave renorm every 32 steps.

#define VV 64
#define L2E 1.4426950408889634f
#define LN2D 0.6931471805599453
#define CH 8

// ---------------- Kernel A: per-frame lse, block-reduced, 1 atomic/block ---
__global__ __launch_bounds__(256) void lse_kernel(const float4* __restrict__ lg4,
                                                  const int* __restrict__ audio_len,
                                                  double* __restrict__ sumlse,
                                                  float* __restrict__ out,
                                                  int T) {
    if (blockIdx.x == 0 && blockIdx.y == 0 && threadIdx.x == 0) out[0] = 0.0f;
    const int b = blockIdx.y;
    const int tl = threadIdx.x >> 4;   // local frame 0..15
    const int q = threadIdx.x & 15;
    const int t = blockIdx.x * 16 + tl;
    int al = audio_len[b];
    int Tb = ((al + 128) >> 7) >> 1;
    if (Tb < 1) Tb = 1;
    if (Tb > T) Tb = T;

    __shared__ double part[16];
    double v = 0.0;
    if (t < Tb) {
        float4 x = lg4[((size_t)b * T + t) * 16 + q];
        float m = fmaxf(fmaxf(x.x, x.y), fmaxf(x.z, x.w));
        #pragma unroll
        for (int off = 8; off >= 1; off >>= 1) m = fmaxf(m, __shfl_xor(m, off));
        float s = __expf(x.x - m) + __expf(x.y - m) + __expf(x.z - m) + __expf(x.w - m);
        #pragma unroll
        for (int off = 8; off >= 1; off >>= 1) s += __shfl_xor(s, off);
        v = (double)(m + __logf(s));
    }
    if (q == 0) part[tl] = v;
    __syncthreads();
    if (threadIdx.x == 0) {
        double s = 0.0;
        #pragma unroll
        for (int i = 0; i < 16; ++i) s += part[i];
        if (s != 0.0) atomicAdd(&sumlse[b], s);
    }
}

// ---------------- Kernel B: fwd+bwd recursion, 2 waves per example ---------

#define LOADM(E, TB, DIRSGN)                                                    \
    do {                                                                        \
        _Pragma("unroll")                                                       \
        for (int k_ = 0; k_ < CH; ++k_) {                                       \
            int tt_ = (TB) + (DIRSGN) * k_;                                     \
            if (tt_ < 0) tt_ = 0;                                               \
            if (tt_ > tf) tt_ = tf;                                             \
            const float* fr_ = lg + ((size_t)tt_ << 6);                         \
            _Pragma("unroll")                                                   \
            for (int i_ = 0; i_ < 5; ++i_) E[i_][k_] = fr_[sym[i_]];            \
        }                                                                       \
    } while (0)

// convert raw logits -> f32 probabilities e^logit = exp2(logit * log2 e)
#define CONV(E)                                                                 \
    do {                                                                        \
        _Pragma("unroll")                                                       \
        for (int i_ = 0; i_ < 5; ++i_) {                                        \
            _Pragma("unroll")                                                   \
            for (int k_ = 0; k_ < CH; ++k_)                                     \
                E[i_][k_] = __builtin_amdgcn_exp2f(E[i_][k_] * L2E);            \
        }                                                                       \
    } while (0)

#define PROCF(E, STEP0, MASKED)                                                 \
    do {                                                                        \
        _Pragma("unroll")                                                       \
        for (int k_ = 0; k_ < CH; ++k_) {                                       \
            double a_ = __shfl_up(p[4], 1);                                     \
            double b_ = __shfl_up(p[3], 1);                                     \
            if (lane == 0) { a_ = 0.0; b_ = 0.0; }                              \
            double e_[5];                                                       \
            _Pragma("unroll")                                                   \
            for (int i_ = 0; i_ < 5; ++i_) e_[i_] = (double)E[i_][k_];          \
            double n0_ = e_[0] * (p[0] + a_ + skd[0] * b_);                     \
            double n1_ = e_[1] * (p[1] + p[0] + skd[1] * a_);                   \
            double n2_ = e_[2] * (p[2] + p[1] + skd[2] * p[0]);                 \
            double n3_ = e_[3] * (p[3] + p[2] + skd[3] * p[1]);                 \
            double n4_ = e_[4] * (p[4] + p[3] + skd[4] * p[2]);                 \
            if (MASKED) {                                                       \
                bool act_ = ((STEP0) + k_) < nst_;                              \
                p[0] = act_ ? n0_ : p[0]; p[1] = act_ ? n1_ : p[1];             \
                p[2] = act_ ? n2_ : p[2]; p[3] = act_ ? n3_ : p[3];             \
                p[4] = act_ ? n4_ : p[4];                                       \
            } else {                                                            \
                p[0] = n0_; p[1] = n1_; p[2] = n2_; p[3] = n3_; p[4] = n4_;     \
            }                                                                   \
        }                                                                       \
    } while (0)

#define PROCB(E, STEP0, MASKED)                                                 \
    do {                                                                        \
        _Pragma("unroll")                                                       \
        for (int k_ = 0; k_ < CH; ++k_) {                                       \
            /* shuffles first: neighbor p and neighbor emission, off-chain */   \
            double pn0_ = __shfl_down(p[0], 1);                                 \
            double pn1_ = __shfl_down(p[1], 1);                                 \
            float en0_ = __shfl_down(E[0][k_], 1);                              \
            float en1_ = __shfl_down(E[1][k_], 1);                              \
            if (lane == 63) { pn0_ = 0.0; pn1_ = 0.0; }                         \
            double u_[5];                                                       \
            _Pragma("unroll")                                                   \
            for (int i_ = 0; i_ < 5; ++i_) u_[i_] = p[i_] * (double)E[i_][k_];  \
            double u5_ = pn0_ * (double)en0_;                                   \
            double u6_ = pn1_ * (double)en1_;                                   \
            double n0_ = u_[0] + u_[1] + skd[2] * u_[2];                        \
            double n1_ = u_[1] + u_[2] + skd[3] * u_[3];                        \
            double n2_ = u_[2] + u_[3] + skd[4] * u_[4];                        \
            double n3_ = u_[3] + u_[4] + skd[5] * u5_;                          \
            double n4_ = u_[4] + u5_ + skd[6] * u6_;                            \
            if (MASKED) {                                                       \
                bool act_ = ((STEP0) + k_) < nst_;                              \
                p[0] = act_ ? n0_ : p[0]; p[1] = act_ ? n1_ : p[1];             \
                p[2] = act_ ? n2_ : p[2]; p[3] = act_ ? n3_ : p[3];             \
                p[4] = act_ ? n4_ : p[4];                                       \
            } else {                                                            \
                p[0] = n0_; p[1] = n1_; p[2] = n2_; p[3] = n3_; p[4] = n4_;     \
            }                                                                   \
        }                                                                       \
    } while (0)

#define RENORM()                                                                \
    do {                                                                        \
        double mx_ = fmax(fmax(fmax(p[0], p[1]), fmax(p[2], p[3])), p[4]);      \
        int ex_ = (__double2hiint(mx_) >> 20) & 0x7ff;                          \
        _Pragma("unroll")                                                       \
        for (int o_ = 32; o_ >= 1; o_ >>= 1) {                                  \
            int t_ = __shfl_xor(ex_, o_);                                       \
            ex_ = t_ > ex_ ? t_ : ex_;                                          \
        }                                                                       \
        if (ex_ > 0) {                                                          \
            Cexp += ex_ - 1023;                                                 \
            double r_ = __hiloint2double((2046 - ex_) << 20, 0);                \
            _Pragma("unroll")                                                   \
            for (int i_ = 0; i_ < 5; ++i_) p[i_] *= r_;                         \
        }                                                                       \
    } while (0)

__global__ __launch_bounds__(128, 1) void ctc_kernel(const float* __restrict__ lgall,
                                                     const int* __restrict__ audio_len,
                                                     const int* __restrict__ labels,
                                                     const double* __restrict__ sumlse,
                                                     float* __restrict__ out,
                                                     int B, int T, int L) {
    const int b = blockIdx.x;
    const int tid = threadIdx.x;
    const int lane = tid & 63;
    const int wid = tid >> 6;
    const int S = 2 * L + 1;
    const float* lg = lgall + (size_t)b * T * VV;

    int al = audio_len[b];
    int Tb = ((al + 128) >> 7) >> 1;
    if (Tb < 1) Tb = 1;
    if (Tb > T) Tb = T;
    const int tf = Tb - 1;
    const int mid = tf >> 1;   // fwd steps: frames 1..mid ; bwd: frames tf..mid+1

    __shared__ int lab_sh[152];
    __shared__ double beta_sh[324];
    __shared__ double sumlse_sh;
    __shared__ int cexpb_sh;

    for (int k = tid; k < L; k += 128) lab_sh[k] = labels[b * L + k];
    __syncthreads();

    int cnt = 0;
    for (int k = lane; k < L; k += 64) cnt += (lab_sh[k] >= 0) ? 1 : 0;
    #pragma unroll
    for (int off = 32; off >= 1; off >>= 1) cnt += __shfl_xor(cnt, off);
    const int s_last = 2 * cnt;

    // per-state symbols (states 5*lane+i) and skip flags (i up to 6 for bwd)
    int sym[5];
    double skd[7];
    #pragma unroll
    for (int i = 0; i < 7; ++i) {
        int s = lane * 5 + i;
        int sy = 0;
        double sk = 0.0;
        if (s < S && (s & 1)) {
            int lv = lab_sh[s >> 1];
            sy = lv < 0 ? 0 : lv;
            if (s >= 3 && sy != 0) {
                int lv2 = lab_sh[(s >> 1) - 1];
                int s2 = lv2 < 0 ? 0 : lv2;
                sk = (sy != s2) ? 1.0 : 0.0;
            }
        }
        if (i < 5) sym[i] = sy;
        skd[i] = sk;
    }

    double p[5];
    int Cexp = 0;

    if (wid == 0) {
        // ---------------- forward: alpha ----------------
        {   // t = 0 init
            #pragma unroll
            for (int i = 0; i < 5; ++i) {
                float x = lg[sym[i]];
                int s = lane * 5 + i;
                p[i] = (s <= 1) ? (double)__builtin_amdgcn_exp2f(x * L2E) : 0.0;
            }
        }
        const int nst_ = mid;
        if (nst_ > 0) {
            const int nch = (nst_ + CH - 1) / CH;
            float eA[5][CH], eB[5][CH];
            LOADM(eA, 1, +1);
            int base = 1, c = 0, step0 = 0;
            for (;;) {
                if (c + 1 < nch) LOADM(eB, base + CH, +1);
                CONV(eA);
                if (c == nch - 1) { PROCF(eA, step0, 1); break; }
                PROCF(eA, step0, 0);
                ++c; step0 += CH; base += CH;
                if ((c & 3) == 0) RENORM();
                if (c + 1 < nch) LOADM(eA, base + CH, +1);
                CONV(eB);
                if (c == nch - 1) { PROCF(eB, step0, 1); break; }
                PROCF(eB, step0, 0);
                ++c; step0 += CH; base += CH;
                if ((c & 3) == 0) RENORM();
            }
        }
        RENORM();   // keep magnitudes safe for the dot product
    } else {
        // ---------------- backward: beta ----------------
        #pragma unroll
        for (int i = 0; i < 5; ++i) {
            int s = lane * 5 + i;
            p[i] = (s == s_last || s == s_last - 1) ? 1.0 : 0.0;
        }
        const int nst_ = tf - mid;
        if (nst_ > 0) {
            const int nch = (nst_ + CH - 1) / CH;
            float eA[5][CH], eB[5][CH];
            LOADM(eA, tf, -1);
            int base = tf, c = 0, step0 = 0;
            for (;;) {
                if (c + 1 < nch) LOADM(eB, base - CH, -1);
                CONV(eA);
                if (c == nch - 1) { PROCB(eA, step0, 1); break; }
                PROCB(eA, step0, 0);
                ++c; step0 += CH; base -= CH;
                if ((c & 3) == 0) RENORM();
                if (c + 1 < nch) LOADM(eA, base - CH, -1);
                CONV(eB);
                if (c == nch - 1) { PROCB(eB, step0, 1); break; }
                PROCB(eB, step0, 0);
                ++c; step0 += CH; base -= CH;
                if ((c & 3) == 0) RENORM();
            }
        }
        RENORM();
        #pragma unroll
        for (int i = 0; i < 5; ++i) beta_sh[lane * 5 + i] = p[i];
        if (lane == 0) { cexpb_sh = Cexp; sumlse_sh = sumlse[b]; }
    }
    __syncthreads();

    if (wid == 0) {
        double dot = 0.0;
        #pragma unroll
        for (int i = 0; i < 5; ++i) dot += p[i] * beta_sh[lane * 5 + i];
        #pragma unroll
        for (int o = 32; o >= 1; o >>= 1) dot += __shfl_xor(dot, o);
        if (lane == 0) {
            dot = fmax(dot, 1e-290);
            double lp = log(dot) + (double)(Cexp + cexpb_sh) * LN2D - sumlse_sh;
            atomicAdd(out, (float)(-lp / (double)B));
        }
    }
}

extern "C" void kernel_launch(void* const* d_in, const int* in_sizes, int n_in,
                              void* d_out, int out_size, void* d_ws, size_t ws_size,
                              hipStream_t stream) {
    const float* logits = (const float*)d_in[0];
    const int* audio = (const int*)d_in[1];
    const int* labels = (const int*)d_in[2];
    float* out = (float*)d_out;

    int B = in_sizes[1];
    int L = in_sizes[2] / B;
    int T = in_sizes[0] / (B * VV);

    double* sumlse = (double*)d_ws;   // B doubles
    hipMemsetAsync(sumlse, 0, (size_t)B * sizeof(double), stream);

    dim3 gA((T + 15) / 16, B);
    lse_kernel<<<gA, 256, 0, stream>>>((const float4*)logits, audio, sumlse, out, T);
    ctc_kernel<<<B, 128, 0, stream>>>(logits, audio, labels, sumlse, out, B, T, L);
}